// Round 1
// baseline (6997.762 us; speedup 1.0000x reference)
//
#include <hip/hip_runtime.h>
#include <stdint.h>

typedef unsigned long long ull;
typedef unsigned int uint;

#define NPTS 4096
#define NC   256
#define M2C  512
#define NS   16
#define NKJ  (NPTS*NS)   // 65536
#define SLOPE 0.1f
#define GEPS 1e-5f

// ---- workspace layout (in floats) ----
static const size_t OFF_N1   = 0;                                  // normalized knn1 [2][256][4096]
static const size_t OFF_N2   = OFF_N1  + (size_t)2*NC*NPTS;        // normalized knn2
static const size_t OFF_P11  = OFF_N2  + (size_t)2*NC*NPTS;        // t11(feat1) [2][256][4096]
static const size_t OFF_P22  = OFF_P11 + (size_t)2*NC*NPTS;        // t22(feat2)
static const size_t OFF_Q11  = OFF_P22 + (size_t)2*NC*NPTS;        // t11(feat2)
static const size_t OFF_Q22  = OFF_Q11 + (size_t)2*NC*NPTS;        // t22(feat1)
static const size_t OFF_WT11 = OFF_Q22 + (size_t)2*NC*NPTS;        // t11_w^T [256][256]
static const size_t OFF_WT22 = OFF_WT11 + 65536;
static const size_t OFF_WTC1 = OFF_WT22 + 65536;                   // conv1_w^T [256][256]
static const size_t OFF_WTC2 = OFF_WTC1 + 65536;                   // conv2_w^T [256][512]
static const size_t OFF_SS   = OFF_WTC2 + 131072;                  // scale/shift 2048 floats
static const size_t OFF_ST   = OFF_SS + 2048;                      // stats 4 iters * 128
static const size_t OFF_IDX  = OFF_ST + 512;                       // knn idx (ints) 4*4096*16
static const size_t OFF_X1   = OFF_IDX + 262144;                   // x1 [256][65536]
static const size_t OFF_BIG  = OFF_X1 + 16777216;                  // x0 (first half) / x2 [512][65536]

// ============ transpose weights [O][C] -> [C][O] ============
__global__ __launch_bounds__(256) void k_transpose(const float* w11, const float* w22,
                                                   const float* wc1, const float* wc2, float* ws) {
    int z = blockIdx.y;
    const float* src; float* dst; int O, Cc;
    if (z == 0)      { src = w11; dst = ws + OFF_WT11; O = 256; Cc = 256; }
    else if (z == 1) { src = w22; dst = ws + OFF_WT22; O = 256; Cc = 256; }
    else if (z == 2) { src = wc1; dst = ws + OFF_WTC1; O = 256; Cc = 256; }
    else             { src = wc2; dst = ws + OFF_WTC2; O = 512; Cc = 256; }
    int flat = blockIdx.x * 256 + threadIdx.x;
    if (flat < O * Cc) {
        int o = flat / Cc, c = flat % Cc;
        dst[(size_t)c * O + o] = src[flat];
    }
}

// ============ normalize knn features along channel dim ============
__global__ __launch_bounds__(256) void k_normalize(const float* knn1, const float* knn2, float* ws) {
    int y = blockIdx.y;                 // 0..3 : tensor = y>>1, batch = y&1
    const float* src = (y >> 1) ? knn2 : knn1;
    float* dst = ws + ((y >> 1) ? OFF_N2 : OFF_N1);
    int b = y & 1;
    src += (size_t)b * NC * NPTS; dst += (size_t)b * NC * NPTS;
    int n = blockIdx.x * 256 + threadIdx.x;
    float ss = 0.f;
    for (int c = 0; c < NC; ++c) { float v = src[(size_t)c * NPTS + n]; ss = fmaf(v, v, ss); }
    float r = 1.f / fmaxf(sqrtf(ss), 1e-8f);
    for (int c = 0; c < NC; ++c) dst[(size_t)c * NPTS + n] = src[(size_t)c * NPTS + n] * r;
}

// ============ top-8 helpers (u64 = dist_bits<<32 | idx, lexicographic == np tiebreak) ============
__device__ __forceinline__ void topk_insert(ull* sl, ull& cm, float d, uint m) {
    ull cand = ((ull)__float_as_uint(d) << 32) | (ull)m;
    if (cand < cm) {
        bool done = false;
#pragma unroll
        for (int l = 0; l < 8; ++l) {
            bool rep = (!done) && (sl[l] == cm);
            if (rep) sl[l] = cand;
            done = done || rep;
        }
        cm = sl[0];
#pragma unroll
        for (int l = 1; l < 8; ++l) cm = (sl[l] > cm) ? sl[l] : cm;
    }
}

__device__ __forceinline__ void topk_merge(ull (&s8)[4][8], ull* mg, int* knn,
                                           size_t knnbase, int r0, int slot0, int tid) {
    int tx = tid & 31, ty = tid >> 5;
    for (int half = 0; half < 2; ++half) {
        __syncthreads();
        if ((ty >> 2) == half) {
#pragma unroll
            for (int i = 0; i < 4; ++i) {
                int ri = (ty & 3) * 4 + i;
#pragma unroll
                for (int l = 0; l < 8; ++l) mg[ri * 256 + tx * 8 + l] = s8[i][l];
            }
        }
        __syncthreads();
        int row16 = tid >> 4, sub = tid & 15;
        for (int round = 0; round < 8; ++round) {
            ull best = ~0ull; int bq = sub * 16;
#pragma unroll
            for (int q = 0; q < 16; ++q) {
                ull v = mg[row16 * 256 + sub * 16 + q];
                if (v < best) { best = v; bq = sub * 16 + q; }
            }
#pragma unroll
            for (int off = 8; off; off >>= 1) {
                ull ov = __shfl_down(best, off, 16);
                int oq = __shfl_down(bq, off, 16);
                if (ov < best) { best = ov; bq = oq; }
            }
            if (sub == 0) {
                mg[row16 * 256 + bq] = ~0ull;
                knn[knnbase + (size_t)(r0 + half * 16 + row16) * NS + slot0 + round] =
                    (int)(best & 0xFFFFFFFFull);
            }
            __syncthreads();
        }
    }
}

// ============ fused distance matrices + exact top-8 (feat & point) ============
__global__ __launch_bounds__(256) void k_dist_topk(const float* __restrict__ n1w, const float* __restrict__ n2w,
                                                   const float* __restrict__ pc1, const float* __restrict__ pc2,
                                                   int* __restrict__ knn) {
    __shared__ ull smem[4096];          // 32 KB, unioned
    float* smem_f = (float*)smem;
    float* a_s = smem_f;                // [16][36]
    float* b_s = smem_f + 16 * 36;      // [16][132]
    ull*   mg  = smem;                  // [16][256]
    float* x1s = smem_f;                // [3][32]
    float* x2s = smem_f + 96;           // [3][128]

    int tid = threadIdx.x;
    int it = blockIdx.y;                // 0..3: dir = it>>1, b = it&1
    int dir = it >> 1, b = it & 1;
    const float* A  = (dir ? n2w : n1w) + (size_t)b * NC * NPTS;
    const float* Bf = (dir ? n1w : n2w) + (size_t)b * NC * NPTS;
    const float* x1p = (dir ? pc2 : pc1) + (size_t)b * 3 * NPTS;
    const float* x2p = (dir ? pc1 : pc2) + (size_t)b * 3 * NPTS;
    size_t knnbase = (size_t)it * NPTS * NS;
    int r0 = blockIdx.x * 32;
    int tx = tid & 31, ty = tid >> 5;

    ull s8[4][8]; ull cmax[4];
#pragma unroll
    for (int i = 0; i < 4; ++i) { cmax[i] = ~0ull;
#pragma unroll
        for (int l = 0; l < 8; ++l) s8[i][l] = ~0ull; }

    // ---------- FEAT phase: dot(A_row, B_col), d = 1 - dot ----------
    for (int ct = 0; ct < 32; ++ct) {
        float acc[4][4] = {};
        for (int kt = 0; kt < 16; ++kt) {
            int c0 = kt * 16;
            { // stage A tile 16x32
                int cc = tid >> 5, r = tid & 31;
                a_s[cc * 36 + r]       = A[(size_t)(c0 + cc) * NPTS + r0 + r];
                a_s[(cc + 8) * 36 + r] = A[(size_t)(c0 + cc + 8) * NPTS + r0 + r];
            }
#pragma unroll
            for (int q = 0; q < 8; ++q) { // stage B tile 16x128
                int flat = q * 256 + tid;
                int cc = flat >> 7, col = flat & 127;
                b_s[cc * 132 + col] = Bf[(size_t)(c0 + cc) * NPTS + ct * 128 + col];
            }
            __syncthreads();
#pragma unroll
            for (int kk = 0; kk < 16; ++kk) {
                float4 a4 = *reinterpret_cast<const float4*>(&a_s[kk * 36 + ty * 4]);
                float4 b4 = *reinterpret_cast<const float4*>(&b_s[kk * 132 + tx * 4]);
                float ar[4] = {a4.x, a4.y, a4.z, a4.w};
                float br[4] = {b4.x, b4.y, b4.z, b4.w};
#pragma unroll
                for (int ii = 0; ii < 4; ++ii)
#pragma unroll
                    for (int jj = 0; jj < 4; ++jj)
                        acc[ii][jj] = fmaf(ar[ii], br[jj], acc[ii][jj]);
            }
            __syncthreads();
        }
#pragma unroll
        for (int ii = 0; ii < 4; ++ii)
#pragma unroll
            for (int jj = 0; jj < 4; ++jj) {
                float d = fmaxf(1.0f - acc[ii][jj], 0.0f);
                uint m = (uint)(ct * 128 + tx * 4 + jj);
                topk_insert(&s8[ii][0], cmax[ii], d, m);
            }
    }
    topk_merge(s8, mg, knn, knnbase, r0, 8, tid);   // feat -> slots 8..15

    // ---------- POINT phase: squared euclidean (monotone w/ sqrt) ----------
#pragma unroll
    for (int i = 0; i < 4; ++i) { cmax[i] = ~0ull;
#pragma unroll
        for (int l = 0; l < 8; ++l) s8[i][l] = ~0ull; }
    if (tid < 96) { int aa = tid >> 5, r = tid & 31; x1s[aa * 32 + r] = x1p[(size_t)aa * NPTS + r0 + r]; }
    for (int ct = 0; ct < 32; ++ct) {
        __syncthreads();
#pragma unroll
        for (int q = 0; q < 2; ++q) {
            int flat = q * 256 + tid;
            if (flat < 384) {
                int aa = flat >> 7, col = flat & 127;
                x2s[aa * 128 + col] = x2p[(size_t)aa * NPTS + ct * 128 + col];
            }
        }
        __syncthreads();
#pragma unroll
        for (int ii = 0; ii < 4; ++ii) {
            float px = x1s[ty * 4 + ii], py = x1s[32 + ty * 4 + ii], pz = x1s[64 + ty * 4 + ii];
#pragma unroll
            for (int jj = 0; jj < 4; ++jj) {
                float dx = px - x2s[tx * 4 + jj];
                float dy = py - x2s[128 + tx * 4 + jj];
                float dz = pz - x2s[256 + tx * 4 + jj];
                float d = fmaf(dx, dx, fmaf(dy, dy, dz * dz));
                uint m = (uint)(ct * 128 + tx * 4 + jj);
                topk_insert(&s8[ii][0], cmax[ii], d, m);
            }
        }
    }
    topk_merge(s8, mg, knn, knnbase, r0, 0, tid);   // point -> slots 0..7
}

// ============ generic fused GEMM: out[o][j] = sum_k At[k][o] * f(Bm[k][j]) + bias[o] ============
// f = optional per-k affine (gn fold) + leaky; optional groupnorm stats on output.
__global__ __launch_bounds__(256) void k_gemm(const float* __restrict__ At, const float* __restrict__ Bm,
                                              const float* __restrict__ bias,
                                              const float* __restrict__ ssc, const float* __restrict__ ssh,
                                              float* __restrict__ outp, float* __restrict__ stats,
                                              int O, int J, int Kd, int leakin) {
    __shared__ float a_s[16][68];
    __shared__ float b_s[16][68];
    int tid = threadIdx.x;
    int tx = tid & 15, ty = tid >> 4;
    int j0 = blockIdx.x * 64, o0 = blockIdx.y * 64;
    float acc[4][4] = {};
    for (int c0 = 0; c0 < Kd; c0 += 16) {
#pragma unroll
        for (int i = 0; i < 4; ++i) {
            int flat = tid + i * 256;
            int kk = flat >> 6, oo = flat & 63;
            a_s[kk][oo] = At[(size_t)(c0 + kk) * O + o0 + oo];
        }
#pragma unroll
        for (int i = 0; i < 4; ++i) {
            int flat = tid + i * 256;
            int kk = flat >> 6, jj = flat & 63;
            float v = Bm[(size_t)(c0 + kk) * J + j0 + jj];
            if (ssc) {
                int c = c0 + kk;
                v = fmaf(v, ssc[c], ssh[c]);
                if (leakin) v = fmaxf(v, SLOPE * v);
            }
            b_s[kk][jj] = v;
        }
        __syncthreads();
#pragma unroll
        for (int kk = 0; kk < 16; ++kk) {
            float4 a4 = *reinterpret_cast<const float4*>(&a_s[kk][ty * 4]);
            float4 b4 = *reinterpret_cast<const float4*>(&b_s[kk][tx * 4]);
            float ar[4] = {a4.x, a4.y, a4.z, a4.w};
            float br[4] = {b4.x, b4.y, b4.z, b4.w};
#pragma unroll
            for (int ii = 0; ii < 4; ++ii)
#pragma unroll
                for (int jj = 0; jj < 4; ++jj)
                    acc[ii][jj] = fmaf(ar[ii], br[jj], acc[ii][jj]);
        }
        __syncthreads();
    }
    float s_sum = 0.f, s_sq = 0.f;
#pragma unroll
    for (int ii = 0; ii < 4; ++ii) {
        int o = o0 + ty * 4 + ii;
        float bb = bias[o];
        float4 r;
        r.x = acc[ii][0] + bb; r.y = acc[ii][1] + bb; r.z = acc[ii][2] + bb; r.w = acc[ii][3] + bb;
        *reinterpret_cast<float4*>(&outp[(size_t)o * J + j0 + tx * 4]) = r;
        if (stats) {
            s_sum += r.x + r.y + r.z + r.w;
            s_sq  += r.x * r.x + r.y * r.y + r.z * r.z + r.w * r.w;
        }
    }
    if (stats) {
#pragma unroll
        for (int off = 32; off; off >>= 1) {
            s_sum += __shfl_down(s_sum, off);
            s_sq  += __shfl_down(s_sq, off);
        }
        if ((tid & 63) == 0) {
            int g = (o0 >> 4) + (tid >> 6);     // each wave's 64 outputs lie in one 16-ch group
            atomicAdd(&stats[2 * g], s_sum);
            atomicAdd(&stats[2 * g + 1], s_sq);
        }
    }
}

// ============ build x0 = grouped_p2 + p1 + pos_w*dir_xyz + pos_b ; accumulate gn0 stats ============
__global__ __launch_bounds__(256) void k_build_x0(const float* __restrict__ P1, const float* __restrict__ P2,
                                                  const float* __restrict__ xyz1, const float* __restrict__ xyz2,
                                                  const int* __restrict__ idx,
                                                  const float* __restrict__ pos_w, const float* __restrict__ pos_b,
                                                  float* __restrict__ x0, float* __restrict__ stats) {
    __shared__ float pw[768];
    __shared__ float pb[256];
    int tid = threadIdx.x;
    pw[tid] = pos_w[tid]; pw[256 + tid] = pos_w[256 + tid]; pw[512 + tid] = pos_w[512 + tid];
    pb[tid] = pos_b[tid];
    __syncthreads();
    int j = blockIdx.x * 256 + tid;
    int n = j >> 4, kk = j & 15;
    int m = idx[n * NS + kk];
    float dx = xyz2[m] - xyz1[n];
    float dy = xyz2[NPTS + m] - xyz1[NPTS + n];
    float dz = xyz2[2 * NPTS + m] - xyz1[2 * NPTS + n];
    float gs = 0.f, gss = 0.f;
    for (int c = 0; c < NC; ++c) {
        float v = P2[(size_t)c * NPTS + m] + P1[(size_t)c * NPTS + n];
        v = fmaf(pw[c * 3], dx, v);
        v = fmaf(pw[c * 3 + 1], dy, v);
        v = fmaf(pw[c * 3 + 2], dz, v);
        v += pb[c];
        x0[(size_t)c * NKJ + j] = v;
        gs += v; gss = fmaf(v, v, gss);
        if ((c & 15) == 15) {
#pragma unroll
            for (int off = 32; off; off >>= 1) {
                gs += __shfl_down(gs, off);
                gss += __shfl_down(gss, off);
            }
            if ((tid & 63) == 0) {
                int g = c >> 4;
                atomicAdd(&stats[2 * g], gs);
                atomicAdd(&stats[2 * g + 1], gss);
            }
            gs = 0.f; gss = 0.f;
        }
    }
}

// ============ finalize gn stats -> per-channel scale/shift ============
__global__ void k_finalize(const float* __restrict__ stats, const float* __restrict__ gamma,
                           const float* __restrict__ beta, float* __restrict__ sc,
                           float* __restrict__ sh, int Cn) {
    int c = blockIdx.x * 256 + threadIdx.x;
    if (c >= Cn) return;
    int g = c >> 4;
    const float inv = 1.0f / 1048576.0f;     // 16 channels * 4096 * 16
    float mean = stats[2 * g] * inv;
    float var = stats[2 * g + 1] * inv - mean * mean;
    float rs = rsqrtf(var + GEPS);
    float s = gamma[c] * rs;
    sc[c] = s;
    sh[c] = beta[c] - mean * s;
}

// ============ epilogue: out[o][n] = max_k leaky(affine(x2[o][n*16+k])) ============
__global__ __launch_bounds__(256) void k_final_max(const float* __restrict__ x2, const float* __restrict__ sc,
                                                   const float* __restrict__ sh, float* __restrict__ outp) {
    int flat = blockIdx.x * 256 + threadIdx.x;
    int o = flat >> 12, n = flat & (NPTS - 1);
    float s = sc[o], h = sh[o];
    const float4* p = reinterpret_cast<const float4*>(&x2[(size_t)o * NKJ + n * NS]);
    float mx = -3.4e38f;
#pragma unroll
    for (int q = 0; q < 4; ++q) {
        float4 v = p[q];
        float t;
        t = fmaf(v.x, s, h); t = fmaxf(t, SLOPE * t); mx = fmaxf(mx, t);
        t = fmaf(v.y, s, h); t = fmaxf(t, SLOPE * t); mx = fmaxf(mx, t);
        t = fmaf(v.z, s, h); t = fmaxf(t, SLOPE * t); mx = fmaxf(mx, t);
        t = fmaf(v.w, s, h); t = fmaxf(t, SLOPE * t); mx = fmaxf(mx, t);
    }
    outp[(size_t)o * NPTS + n] = mx;
}

extern "C" void kernel_launch(void* const* d_in, const int* in_sizes, int n_in,
                              void* d_out, int out_size, void* d_ws, size_t ws_size,
                              hipStream_t stream) {
    const float* pc1   = (const float*)d_in[0];
    const float* pc2   = (const float*)d_in[1];
    const float* feat1 = (const float*)d_in[2];
    const float* feat2 = (const float*)d_in[3];
    const float* knn1  = (const float*)d_in[4];
    const float* knn2  = (const float*)d_in[5];
    const float* t11_w = (const float*)d_in[6];
    const float* t11_b = (const float*)d_in[7];
    const float* t22_w = (const float*)d_in[8];
    const float* t22_b = (const float*)d_in[9];
    const float* pos_w = (const float*)d_in[10];
    const float* pos_b = (const float*)d_in[11];
    const float* gn0_w = (const float*)d_in[12];
    const float* gn0_b = (const float*)d_in[13];
    const float* c1_w  = (const float*)d_in[14];
    const float* c1_b  = (const float*)d_in[15];
    const float* gn1_w = (const float*)d_in[16];
    const float* gn1_b = (const float*)d_in[17];
    const float* c2_w  = (const float*)d_in[18];
    const float* c2_b  = (const float*)d_in[19];
    const float* gn2_w = (const float*)d_in[20];
    const float* gn2_b = (const float*)d_in[21];
    float* ws = (float*)d_ws;
    float* outp = (float*)d_out;

    hipMemsetAsync(ws + OFF_ST, 0, 512 * sizeof(float), stream);
    k_transpose<<<dim3(512, 4), 256, 0, stream>>>(t11_w, t22_w, c1_w, c2_w, ws);
    k_normalize<<<dim3(16, 4), 256, 0, stream>>>(knn1, knn2, ws);
    k_dist_topk<<<dim3(128, 4), 256, 0, stream>>>(ws + OFF_N1, ws + OFF_N2, pc1, pc2,
                                                  (int*)(ws + OFF_IDX));

    // p/q 1x1 convs: P11=t11(feat1), P22=t22(feat2), Q11=t11(feat2), Q22=t22(feat1)
    const float* pqAt[4]   = { ws + OFF_WT11, ws + OFF_WT22, ws + OFF_WT11, ws + OFF_WT22 };
    const float* pqBm[4]   = { feat1, feat2, feat2, feat1 };
    const float* pqBias[4] = { t11_b, t22_b, t11_b, t22_b };
    size_t pqDst[4] = { OFF_P11, OFF_P22, OFF_Q11, OFF_Q22 };
    for (int q = 0; q < 4; ++q)
        for (int b = 0; b < 2; ++b)
            k_gemm<<<dim3(64, 4), 256, 0, stream>>>(pqAt[q], pqBm[q] + (size_t)b * NC * NPTS,
                pqBias[q], nullptr, nullptr, ws + pqDst[q] + (size_t)b * NC * NPTS,
                nullptr, 256, NPTS, 256, 0);

    float* x0 = ws + OFF_BIG;
    float* x1 = ws + OFF_X1;
    float* x2 = ws + OFF_BIG;     // overlays x0 (dead after conv1)
    float* sc0 = ws + OFF_SS; float* sh0 = sc0 + 256;
    float* sc1 = sc0 + 512;   float* sh1 = sc0 + 768;
    float* sc2 = sc0 + 1024;  float* sh2 = sc0 + 1536;

    for (int itx = 0; itx < 4; ++itx) {
        int dir = itx >> 1, b = itx & 1;
        const float* P1 = ws + (dir ? OFF_Q11 : OFF_P11) + (size_t)b * NC * NPTS;
        const float* P2 = ws + (dir ? OFF_Q22 : OFF_P22) + (size_t)b * NC * NPTS;
        const float* xyz1 = (dir ? pc2 : pc1) + (size_t)b * 3 * NPTS;
        const float* xyz2 = (dir ? pc1 : pc2) + (size_t)b * 3 * NPTS;
        const int* idx = (const int*)(ws + OFF_IDX) + (size_t)itx * NPTS * NS;
        float* st = ws + OFF_ST + itx * 128;

        k_build_x0<<<dim3(256), 256, 0, stream>>>(P1, P2, xyz1, xyz2, idx, pos_w, pos_b, x0, st);
        k_finalize<<<dim3(1), 256, 0, stream>>>(st, gn0_w, gn0_b, sc0, sh0, 256);
        k_gemm<<<dim3(1024, 4), 256, 0, stream>>>(ws + OFF_WTC1, x0, c1_b, sc0, sh0,
                                                  x1, st + 32, 256, NKJ, 256, 1);
        k_finalize<<<dim3(1), 256, 0, stream>>>(st + 32, gn1_w, gn1_b, sc1, sh1, 256);
        k_gemm<<<dim3(1024, 8), 256, 0, stream>>>(ws + OFF_WTC2, x1, c2_b, sc1, sh1,
                                                  x2, st + 64, 512, NKJ, 256, 1);
        k_finalize<<<dim3(2), 256, 0, stream>>>(st + 64, gn2_w, gn2_b, sc2, sh2, 512);
        k_final_max<<<dim3(8192), 256, 0, stream>>>(x2, sc2, sh2, outp + (size_t)itx * M2C * NPTS);
    }
}